// Round 1
// baseline (325.061 us; speedup 1.0000x reference)
//
#include <hip/hip_runtime.h>
#include <stdint.h>

typedef float f32x4 __attribute__((ext_vector_type(4)));
typedef short bf16x8 __attribute__((ext_vector_type(8)));
typedef unsigned short u16;

static constexpr int kB  = 16384;
static constexpr int kDC = 2048;
static constexpr int kNF = 768;
static constexpr float kEps = 1e-5f;

// ---- workspace layout (bytes). Region X at OFF_AXBF is reused by liveness:
//  Axbf (prep->gemm1) -> H (gemmH->att) -> G (gemmG->combine)
static constexpr size_t OFF_FEATS  = 0;                       // [3][B][768] bf16 = 75,497,472
static constexpr size_t OFF_AXBF   = 75497472;                // 67,108,864 (X)
static constexpr size_t OFF_WCBF   = OFF_AXBF + 67108864;     // 3,145,728
static constexpr size_t OFF_WA1BF  = OFF_WCBF + 3145728;      // 196,608
static constexpr size_t OFF_W1BF   = OFF_WA1BF + 196608;      // 1,179,648
static constexpr size_t OFF_FUSE   = OFF_W1BF + 1179648;      // [B][256] f32 = 16,777,216
static constexpr size_t OFF_SCORES = OFF_FUSE + 16777216;     // [B][3] f32 (padded) = 196,608
static constexpr size_t OFF_STATS  = OFF_SCORES + 196608;     // 3072 (hstats) + 2048 (fstats)

static __device__ __forceinline__ u16 f2bf(float x) {
  union { float f; unsigned u; } c; c.f = x;
  unsigned r = c.u + 0x7fffu + ((c.u >> 16) & 1u);
  return (u16)(r >> 16);
}

static __device__ __forceinline__ void cvt4(const float* __restrict__ in, u16* __restrict__ out, long v) {
  const float4 f = ((const float4*)in)[v];
  ((ushort4*)out)[v] = make_ushort4(f2bf(f.x), f2bf(f.y), f2bf(f.z), f2bf(f.w));
}

// ---------------- prep: fp32 -> bf16 conversions (+ face repeat) ----------------
__global__ __launch_bounds__(256) void prep_kernel(
    const float* __restrict__ xc, const float* __restrict__ xb, const float* __restrict__ xf,
    const float* __restrict__ Wc, const float* __restrict__ Wa1, const float* __restrict__ W1,
    u16* __restrict__ axbf, u16* __restrict__ feats,
    u16* __restrict__ wcbf, u16* __restrict__ wa1bf, u16* __restrict__ w1bf)
{
  const long U0 = 8388608, U1 = 3145728, U2 = 1048576, U3 = 393216, U4 = 24576, U5 = 147456;
  const long total = U0 + U1 + U2 + U3 + U4 + U5;
  for (long u = (long)blockIdx.x * blockDim.x + threadIdx.x; u < total;
       u += (long)gridDim.x * blockDim.x) {
    long v = u;
    if (v < U0) { cvt4(xc, axbf, v); continue; }
    v -= U0;
    if (v < U1) { cvt4(xb, feats + (size_t)kB * kNF, v); continue; }
    v -= U1;
    if (v < U2) {
      // face: out[row][3c+d] = in[row][c], 4 inputs -> 12 consecutive bf16
      const float4 f = ((const float4*)xf)[v];
      u16 a = f2bf(f.x), b = f2bf(f.y), c = f2bf(f.z), d = f2bf(f.w);
      size_t p = (size_t)v * 4;
      size_t row = p >> 8;
      int col = (int)(p & 255);
      u16* o = feats + (size_t)2 * kB * kNF + row * kNF + col * 3;
      ushort4* o4 = (ushort4*)o;
      o4[0] = make_ushort4(a, a, a, b);
      o4[1] = make_ushort4(b, b, c, c);
      o4[2] = make_ushort4(c, d, d, d);
      continue;
    }
    v -= U2;
    if (v < U3) { cvt4(Wc, wcbf, v); continue; }
    v -= U3;
    if (v < U4) { cvt4(Wa1, wa1bf, v); continue; }
    v -= U4;
    cvt4(W1, w1bf, v);
  }
}

// ---------------- MFMA GEMM, C = A @ B^T (+bias), m97-style 128x128 tile ----------------
static __device__ __forceinline__ void gload16(const void* g, void* l) {
  __builtin_amdgcn_global_load_lds(
      (const __attribute__((address_space(1))) void*)g,
      (__attribute__((address_space(3))) void*)l, 16, 0, 0);
}

template <int OUT_BF16>
__global__ __launch_bounds__(256) void gemm_bt(
    const u16* __restrict__ A, int lda, const u16* __restrict__ B, int ldb,
    const float* __restrict__ bias, void* __restrict__ Cv, int ldc, int K,
    int blocksPerChunk, int bChunkOff)
{
  __shared__ __align__(16) u16 As[128 * 32];
  __shared__ __align__(16) u16 Bs[128 * 32];
  const int bx = blockIdx.x, by = blockIdx.y;
  const u16* Bp = B + (size_t)(bx / blocksPerChunk) * bChunkOff;
  const size_t m0 = (size_t)bx * 128;
  const int n0 = by * 128;
  const int t = threadIdx.x;
  const int lane = t & 63, wave = t >> 6;
  const int wm = (wave >> 1) * 64, wn = (wave & 1) * 64;
  const int fr = lane & 15, fq = lane >> 4;

  const int srow = t >> 2;          // staging row 0..63
  const int scol = (t & 3) * 8;     // staging col (elements)
  const u16* ga0 = A + (m0 + srow) * (size_t)lda + scol;
  const u16* ga1 = A + (m0 + 64 + srow) * (size_t)lda + scol;
  const u16* gb0 = Bp + (size_t)(n0 + srow) * ldb + scol;
  const u16* gb1 = Bp + (size_t)(n0 + 64 + srow) * ldb + scol;
  u16* la = As + t * 8;             // lds dest = wave base + lane*16B (linear)
  u16* lb = Bs + t * 8;
  const u16* fa = As + (wm + fr) * 32 + fq * 8;
  const u16* fb = Bs + (wn + fr) * 32 + fq * 8;

  f32x4 acc[4][4] = {};

  const int kt = K >> 5;
  for (int k = 0; k < kt; ++k) {
    __syncthreads();
    gload16(ga0, la);
    gload16(ga1, la + 2048);
    gload16(gb0, lb);
    gload16(gb1, lb + 2048);
    ga0 += 32; ga1 += 32; gb0 += 32; gb1 += 32;
    __syncthreads();
    bf16x8 av[4], bv[4];
#pragma unroll
    for (int mf = 0; mf < 4; ++mf) av[mf] = *(const bf16x8*)(fa + mf * 512);
#pragma unroll
    for (int nf = 0; nf < 4; ++nf) bv[nf] = *(const bf16x8*)(fb + nf * 512);
#pragma unroll
    for (int mf = 0; mf < 4; ++mf)
#pragma unroll
      for (int nf = 0; nf < 4; ++nf)
        acc[mf][nf] = __builtin_amdgcn_mfma_f32_16x16x32_bf16(av[mf], bv[nf], acc[mf][nf], 0, 0, 0);
  }

#pragma unroll
  for (int mf = 0; mf < 4; ++mf) {
    const size_t rb = m0 + wm + mf * 16 + fq * 4;
#pragma unroll
    for (int nf = 0; nf < 4; ++nf) {
      const int gn = n0 + wn + nf * 16 + fr;
      const float bb = bias ? bias[gn] : 0.0f;
#pragma unroll
      for (int rr = 0; rr < 4; ++rr) {
        const float vv = acc[mf][nf][rr] + bb;
        if (OUT_BF16) ((u16*)Cv)[(rb + rr) * (size_t)ldc + gn] = f2bf(vv);
        else ((float*)Cv)[(rb + rr) * (size_t)ldc + gn] = vv;
      }
    }
  }
}

// ---------------- H column stats (sum, sumsq) per feat ----------------
__global__ __launch_bounds__(256) void hstats_kernel(const float* __restrict__ H, float* __restrict__ stats) {
  const int blk = blockIdx.x;
  const int f = blk >> 8;          // 256 chunks per feat
  const int chunk = blk & 255;
  const int t = threadIdx.x;
  const int col = t & 127, rh = t >> 7;
  const float* base = H + ((size_t)f * kB + (size_t)chunk * 64) * 128;
  float s = 0.f, s2 = 0.f;
  for (int r = rh; r < 64; r += 2) {
    float v = base[r * 128 + col];
    s += v; s2 += v * v;
  }
  __shared__ float sh[256], sh2[256];
  sh[t] = s; sh2[t] = s2;
  __syncthreads();
  if (t < 128) {
    s = sh[t] + sh[t + 128];
    s2 = sh2[t] + sh2[t + 128];
    atomicAdd(&stats[(f * 128 + col) * 2 + 0], s);
    atomicAdd(&stats[(f * 128 + col) * 2 + 1], s2);
  }
}

// ---------------- attention scores: bn+gelu+dot (x3) + softmax ----------------
__global__ __launch_bounds__(64) void att_kernel(
    const float* __restrict__ H, const float* __restrict__ stats,
    const float* __restrict__ ga, const float* __restrict__ bba,
    const float* __restrict__ Wa2, const float* __restrict__ ba2,
    float* __restrict__ scores)
{
  const int i = blockIdx.x, l = threadIdx.x;
  float d[3];
#pragma unroll
  for (int f = 0; f < 3; ++f) {
    float part = 0.f;
#pragma unroll
    for (int h = 0; h < 2; ++h) {
      const int c = l + h * 64;
      const float sum = stats[(f * 128 + c) * 2 + 0];
      const float sq  = stats[(f * 128 + c) * 2 + 1];
      const float m = sum * (1.f / kB);
      const float var = sq * (1.f / kB) - m * m;
      const float rs = rsqrtf(var + kEps);
      const float x = H[((size_t)f * kB + i) * 128 + c];
      const float xn = (x - m) * rs * ga[c] + bba[c];
      const float ge = 0.5f * xn * (1.f + erff(xn * 0.70710678118f));
      part += ge * Wa2[c];
    }
#pragma unroll
    for (int off = 32; off > 0; off >>= 1) part += __shfl_down(part, off);
    d[f] = part;
  }
  if (l == 0) {
    const float b2 = ba2[0];
    float d0 = d[0] + b2, d1 = d[1] + b2, d2 = d[2] + b2;
    const float mx = fmaxf(d0, fmaxf(d1, d2));
    const float e0 = expf(d0 - mx), e1 = expf(d1 - mx), e2 = expf(d2 - mx);
    const float inv = 1.f / (e0 + e1 + e2);
    scores[i * 3 + 0] = e0 * inv;
    scores[i * 3 + 1] = e1 * inv;
    scores[i * 3 + 2] = e2 * inv;
  }
}

// ---------------- combine: fuse = s0*Gc + s1*Gb + s2*Gf + b1, + column stats ----------------
__global__ __launch_bounds__(256) void combine_kernel(
    const float* __restrict__ G, const float* __restrict__ scores,
    const float* __restrict__ b1, float* __restrict__ fuse, float* __restrict__ fstats)
{
  const int t = threadIdx.x;
  const int r0 = blockIdx.x * 32;
  const float bb = b1[t];
  float s = 0.f, s2 = 0.f;
  for (int r = 0; r < 32; ++r) {
    const int i = r0 + r;
    const float s0 = scores[i * 3 + 0], s1 = scores[i * 3 + 1], sc2 = scores[i * 3 + 2];
    const size_t o = (size_t)i * 256 + t;
    const float v = s0 * G[o] + s1 * G[o + (size_t)kB * 256] + sc2 * G[o + (size_t)2 * kB * 256] + bb;
    fuse[o] = v;
    s += v; s2 += v * v;
  }
  atomicAdd(&fstats[t * 2 + 0], s);
  atomicAdd(&fstats[t * 2 + 1], s2);
}

// ---------------- final: bn + relu + [256 -> 26] ----------------
__global__ __launch_bounds__(64) void final_kernel(
    const float* __restrict__ fuse, const float* __restrict__ fstats,
    const float* __restrict__ g1, const float* __restrict__ be1,
    const float* __restrict__ Wcat, const float* __restrict__ bcat,
    float* __restrict__ out)
{
  const int i = blockIdx.x, l = threadIdx.x;
  __shared__ float row[256];
#pragma unroll
  for (int h = 0; h < 4; ++h) {
    const int c = l + h * 64;
    const float sum = fstats[c * 2 + 0], sq = fstats[c * 2 + 1];
    const float m = sum * (1.f / kB);
    const float var = sq * (1.f / kB) - m * m;
    const float rs = rsqrtf(var + kEps);
    const float v = (fuse[(size_t)i * 256 + c] - m) * rs * g1[c] + be1[c];
    row[c] = fmaxf(v, 0.f);
  }
  __syncthreads();
  if (l < 26) {
    float acc = bcat[l];
    const float* w = Wcat + l * 256;
    for (int k2 = 0; k2 < 256; ++k2) acc += row[k2] * w[k2];
    out[(size_t)i * 26 + l] = acc;
  }
}

extern "C" void kernel_launch(void* const* d_in, const int* in_sizes, int n_in,
                              void* d_out, int out_size, void* d_ws, size_t ws_size,
                              hipStream_t stream) {
  (void)in_sizes; (void)n_in; (void)out_size; (void)ws_size;
  const float* xc   = (const float*)d_in[0];
  const float* xb   = (const float*)d_in[1];
  const float* xf   = (const float*)d_in[2];
  const float* Wc   = (const float*)d_in[3];
  const float* bc   = (const float*)d_in[4];
  const float* Wa1  = (const float*)d_in[5];
  const float* ba1  = (const float*)d_in[6];
  const float* ga   = (const float*)d_in[7];
  const float* bba  = (const float*)d_in[8];
  const float* Wa2  = (const float*)d_in[9];
  const float* ba2  = (const float*)d_in[10];
  const float* W1   = (const float*)d_in[11];
  const float* b1   = (const float*)d_in[12];
  const float* g1   = (const float*)d_in[13];
  const float* be1  = (const float*)d_in[14];
  const float* Wcat = (const float*)d_in[15];
  const float* bcat = (const float*)d_in[16];
  float* out = (float*)d_out;

  char* ws = (char*)d_ws;
  u16* feats   = (u16*)(ws + OFF_FEATS);   // [ctx | body | face] bf16, stacked [3*B][768]
  u16* axbf    = (u16*)(ws + OFF_AXBF);    // region X use #1
  float* H     = (float*)(ws + OFF_AXBF);  // region X use #2: [3*B][128] f32
  float* G     = (float*)(ws + OFF_AXBF);  // region X use #3: [3*B][256] f32
  u16* wcbf    = (u16*)(ws + OFF_WCBF);
  u16* wa1bf   = (u16*)(ws + OFF_WA1BF);
  u16* w1bf    = (u16*)(ws + OFF_W1BF);
  float* fuse  = (float*)(ws + OFF_FUSE);
  float* scores= (float*)(ws + OFF_SCORES);
  float* hst   = (float*)(ws + OFF_STATS);
  float* fst   = (float*)(ws + OFF_STATS + 3072);

  hipMemsetAsync(ws + OFF_STATS, 0, 5120, stream);
  prep_kernel<<<2048, 256, 0, stream>>>(xc, xb, xf, Wc, Wa1, W1, axbf, feats, wcbf, wa1bf, w1bf);
  // ctx = x_context @ Wc^T + bc  (M=16384, N=768, K=2048) -> bf16 into feats[0]
  gemm_bt<1><<<dim3(128, 6), 256, 0, stream>>>(axbf, kDC, wcbf, kDC, bc, feats, kNF, kDC, 1 << 30, 0);
  // H = feats @ Wa1^T + ba1  (M=49152, N=128, K=768) -> f32
  gemm_bt<0><<<dim3(384, 1), 256, 0, stream>>>(feats, kNF, wa1bf, kNF, ba1, H, 128, kNF, 1 << 30, 0);
  hstats_kernel<<<768, 256, 0, stream>>>(H, hst);
  att_kernel<<<kB, 64, 0, stream>>>(H, hst, ga, bba, Wa2, ba2, scores);
  // G_f = feat_f @ W1[:, f*768:(f+1)*768]^T  (M=49152, N=256, K=768) -> f32
  gemm_bt<0><<<dim3(384, 2), 256, 0, stream>>>(feats, kNF, w1bf, 2304, nullptr, G, 256, kNF, 128, kNF);
  combine_kernel<<<512, 256, 0, stream>>>(G, scores, b1, fuse, fst);
  final_kernel<<<kB, 64, 0, stream>>>(fuse, fst, g1, be1, Wcat, bcat, out);
}